// Round 4
// baseline (237.620 us; speedup 1.0000x reference)
//
#include <hip/hip_runtime.h>
#include <math.h>

// Elastic transform: [32,256,1024,3] fp32, 3x3 control grid displacement.
// Pipeline (planar restructure):
//   k_disp   : dense dy/dx fields [256,1024] from 3x3 control points
//   k_wfilt  : cubic spline prefilter along W, reading x (interleaved rows),
//              writing coefP PLANAR [b][c][h][w]  (37-tap mirror FIR)
//   k_hfilt  : prefilter along H, in place on planar tiles (padded LDS)
//   k_sample : 4x4 cubic gather from planar coef; weights/offsets amortized
//              across batch; interior fast path = 12 unaligned dwordx4 loads

#define H_ 256
#define W_ 1024
#define B_ 32
#define RAD 18               // |z|^18 ~ 5e-11, z = sqrt(3)-2
#define ROWF 3072            // W_*3 floats per (b,h) row of x
#define HW_ (H_ * W_)        // 262144 floats per plane
#define NBS 2                // batch splits in k_sample

typedef float f4a __attribute__((ext_vector_type(4), aligned(4)));

__device__ __forceinline__ float b3f(float t) {
    float a = fabsf(t);
    if (a < 1.0f) return (4.0f - 6.0f * a * a + 3.0f * a * a * a) * (1.0f / 6.0f);
    if (a < 2.0f) { float s = 2.0f - a; return s * s * s * (1.0f / 6.0f); }
    return 0.0f;
}

// branch-free cubic weights: w[k] = b3f(f - (k-1)), f in [0,1)
__device__ __forceinline__ void cubw(float f, float* w) {
    float f2 = f * f, f3 = f2 * f;
    float om = 1.0f - f;
    w[0] = om * om * om * (1.0f / 6.0f);
    w[1] = (3.0f * f3 - 6.0f * f2 + 4.0f) * (1.0f / 6.0f);
    w[2] = (-3.0f * f3 + 3.0f * f2 + 3.0f * f + 1.0f) * (1.0f / 6.0f);
    w[3] = f3 * (1.0f / 6.0f);
}

__device__ __forceinline__ float clamp01(float v) {
    return fminf(fmaxf(v, 0.0f), 1.0f);
}

__device__ __forceinline__ void basis3(int i, int n, float& w0, float& w1, float& w2) {
    float u = (float)i * 2.0f / (float)(n - 1);
    int base = (int)floorf(u);
    w0 = w1 = w2 = 0.0f;
#pragma unroll
    for (int k = -1; k < 3; ++k) {
        int id = base + k;
        float bw = b3f(u - (float)id);
        int j = id < 0 ? -id : id;
        j &= 3;
        if (j == 3) j = 1;
        if (j == 0) w0 += bw; else if (j == 1) w1 += bw; else w2 += bw;
    }
}

// ---------------- kernel 0: displacement fields ----------------
__global__ __launch_bounds__(256) void k_disp(const float* __restrict__ disp,
                                              float* __restrict__ dyp,
                                              float* __restrict__ dxp) {
    int idx = blockIdx.x * 256 + threadIdx.x;
    int h = idx >> 10, w = idx & 1023;

    const float A[3][3] = {{1.75f, -1.0f, 0.25f},
                           {-0.5f,  2.0f, -0.5f},
                           {0.25f, -1.0f, 1.75f}};
    float Ty[3][3], Tx[3][3];
#pragma unroll
    for (int i = 0; i < 3; ++i)
#pragma unroll
        for (int j = 0; j < 3; ++j) {
            float ty = 0.f, tx = 0.f;
#pragma unroll
            for (int k = 0; k < 3; ++k) {
                ty += A[i][k] * (5.0f * disp[k * 3 + j]);
                tx += A[i][k] * (5.0f * disp[9 + k * 3 + j]);
            }
            Ty[i][j] = ty; Tx[i][j] = tx;
        }
    float Cy[3][3], Cx[3][3];
#pragma unroll
    for (int i = 0; i < 3; ++i)
#pragma unroll
        for (int j = 0; j < 3; ++j) {
            float ty = 0.f, tx = 0.f;
#pragma unroll
            for (int k = 0; k < 3; ++k) {
                ty += Ty[i][k] * A[j][k];
                tx += Tx[i][k] * A[j][k];
            }
            Cy[i][j] = ty; Cx[i][j] = tx;
        }

    float rh0, rh1, rh2, rw0, rw1, rw2;
    basis3(h, H_, rh0, rh1, rh2);
    basis3(w, W_, rw0, rw1, rw2);
    float rh[3] = {rh0, rh1, rh2}, rw[3] = {rw0, rw1, rw2};

    float dy = 0.f, dx = 0.f;
#pragma unroll
    for (int i = 0; i < 3; ++i)
#pragma unroll
        for (int j = 0; j < 3; ++j) {
            dy += rh[i] * Cy[i][j] * rw[j];
            dx += rh[i] * Cx[i][j] * rw[j];
        }
    dyp[idx] = dy;
    dxp[idx] = dx;
}

// ---------------- kernel 1: prefilter along W, x -> planar coefP ----------
#define PLN 1064
__global__ __launch_bounds__(256) void k_wfilt(const float* __restrict__ x,
                                               float* __restrict__ coefP) {
    __shared__ float pl[3 * PLN];
    const int bp = blockIdx.x;          // b*256 + h
    const int t = threadIdx.x;
    const float* row = x + (size_t)bp * ROWF;

    {
        float4 v0 = *(const float4*)(row + 12 * t);
        float4 v1 = *(const float4*)(row + 12 * t + 4);
        float4 v2 = *(const float4*)(row + 12 * t + 8);
        float vals[12] = {v0.x, v0.y, v0.z, v0.w,
                          v1.x, v1.y, v1.z, v1.w,
                          v2.x, v2.y, v2.z, v2.w};
        const int q0 = 4 * t;
#pragma unroll
        for (int e = 0; e < 12; ++e) {
            pl[(e % 3) * PLN + RAD + q0 + e / 3] = vals[e];   // compile-time e
        }
    }
    __syncthreads();

    if (t < 108) {                   // mirror halos
        int c = t / 36, i2 = t % 36;
        float* p = pl + c * PLN;
        if (i2 < 18) p[i2] = p[36 - i2];
        else { int r2 = i2 - 18; p[1042 + r2] = p[1040 - r2]; }
    }
    __syncthreads();

    float g[RAD + 1];
    g[0] = 1.7320508075688773f;
#pragma unroll
    for (int k = 1; k <= RAD; ++k) g[k] = g[k - 1] * (-0.26794919243112270647f);

    const int b = bp >> 8, h = bp & 255;
    float* dst0 = coefP + ((size_t)(b * 3) * H_ + h) * W_ + 4 * t;

#pragma unroll
    for (int c = 0; c < 3; ++c) {
        const float* p = pl + c * PLN + 4 * t;   // phys index of q0-18
        float w[40];
#pragma unroll
        for (int i = 0; i < 10; ++i) {
            float4 v = *(const float4*)(p + 4 * i);
            w[4 * i] = v.x; w[4 * i + 1] = v.y; w[4 * i + 2] = v.z; w[4 * i + 3] = v.w;
        }
        float4 o;
        float a0 = 0.f, a1 = 0.f, a2 = 0.f, a3 = 0.f;
#pragma unroll
        for (int k = -RAD; k <= RAD; ++k) {
            float gk = g[k < 0 ? -k : k];
            a0 += gk * w[0 + RAD + k];
            a1 += gk * w[1 + RAD + k];
            a2 += gk * w[2 + RAD + k];
            a3 += gk * w[3 + RAD + k];
        }
        o.x = a0; o.y = a1; o.z = a2; o.w = a3;
        *(float4*)(dst0 + (size_t)c * HW_) = o;   // planar, coalesced
    }
}

// ---------------- kernel 2: prefilter along H, in place on planar ---------
// one block per (plane, 32-wide w-chunk); LDS tile [256 rows][40 floats]
// (stride 40 = 160 B: 16B-aligned float4s, 8-bank row rotation -> <=2-way)
#define TSTR 40
__global__ __launch_bounds__(256) void k_hfilt(float* __restrict__ coefP) {
    __shared__ float tile[H_ * TSTR];   // 40 KiB
    const int t = threadIdx.x;
    float* src = coefP + (size_t)blockIdx.y * HW_ + blockIdx.x * 32;

#pragma unroll
    for (int it = 0; it < 8; ++it) {
        int idx = t + it * 256;          // 0..2047 float4s
        int r = idx >> 3, seg = idx & 7;
        *(float4*)(tile + r * TSTR + seg * 4) =
            *(const float4*)(src + (size_t)r * W_ + seg * 4);
    }
    __syncthreads();

    float g[RAD + 1];
    g[0] = 1.7320508075688773f;
#pragma unroll
    for (int k = 1; k <= RAD; ++k) g[k] = g[k - 1] * (-0.26794919243112270647f);

    const int cg = t & 7;          // float4 column group
    const int prow = t >> 3;       // 0..31
    const int p0 = prow * 8;

    float acc[8][4];
#pragma unroll
    for (int j = 0; j < 8; ++j) {
        acc[j][0] = 0.f; acc[j][1] = 0.f; acc[j][2] = 0.f; acc[j][3] = 0.f;
    }

#pragma unroll
    for (int r = 0; r < 8 + 2 * RAD; ++r) {    // 44 rows
        int hh = p0 - RAD + r;
        int m1 = hh < 0 ? -hh : hh;
        int m2 = 2 * (H_ - 1) - hh;            // 510 - hh
        int mp = m1 < m2 ? m1 : m2;
        float4 v = *(const float4*)(tile + mp * TSTR + cg * 4);
#pragma unroll
        for (int j = 0; j < 8; ++j) {
            const int d = r - RAD - j;         // compile-time tap
            if (d >= -RAD && d <= RAD) {
                const float wgt = g[d < 0 ? -d : d];
                acc[j][0] += wgt * v.x;
                acc[j][1] += wgt * v.y;
                acc[j][2] += wgt * v.z;
                acc[j][3] += wgt * v.w;
            }
        }
    }

#pragma unroll
    for (int j = 0; j < 8; ++j) {
        float4 o;
        o.x = acc[j][0]; o.y = acc[j][1]; o.z = acc[j][2]; o.w = acc[j][3];
        *(float4*)(src + (size_t)(p0 + j) * W_ + cg * 4) = o;
    }
}

// ---------------- kernel 3: 4x4 cubic gather from planar coef -------------
// thread owns one (h,w): weights + y-clamped row offsets computed once,
// then B_/NBS batches of {12 unaligned dwordx4 loads + 48 FMA + store}.
__global__ __launch_bounds__(256) void k_sample(const float* __restrict__ coefP,
                                                const float* __restrict__ dyp,
                                                const float* __restrict__ dxp,
                                                float* __restrict__ out) {
    const int idx = blockIdx.x * 256 + threadIdx.x;   // 0..262143
    const int h = idx >> 10, w = idx & 1023;
    const int b0 = blockIdx.y * (B_ / NBS);

    float cy = (float)h + dyp[idx];
    float cx = (float)w + dxp[idx];
    float byf = floorf(cy), bxf = floorf(cx);
    int by = (int)byf, bx = (int)bxf;
    float wy[4], wx[4];
    cubw(cy - byf, wy);
    cubw(cx - bxf, wx);

    float wxy[4][4];
#pragma unroll
    for (int r = 0; r < 4; ++r)
#pragma unroll
        for (int k = 0; k < 4; ++k) wxy[r][k] = wy[r] * wx[k];

    int iyW[4];
#pragma unroll
    for (int r = 0; r < 4; ++r)
        iyW[r] = min(max(by - 1 + r, 0), H_ - 1) * W_;   // y-clamp folded in

    const bool xin = (bx >= 1) && (bx <= W_ - 3);

    const float* cb = coefP + (size_t)(b0 * 3) * HW_;
    float* ob = out + ((size_t)(b0 * H_ + h) * W_ + w) * 3;

    if (xin) {
        int offr[4];
#pragma unroll
        for (int r = 0; r < 4; ++r) offr[r] = iyW[r] + bx - 1;

#pragma unroll 1
        for (int bb = 0; bb < B_ / NBS; ++bb) {
            float a0 = 0.f, a1 = 0.f, a2 = 0.f;
#pragma unroll
            for (int r = 0; r < 4; ++r) {
                f4a v0 = *(const f4a*)(cb + offr[r]);
                f4a v1 = *(const f4a*)(cb + HW_ + offr[r]);
                f4a v2 = *(const f4a*)(cb + 2 * HW_ + offr[r]);
                a0 += wxy[r][0] * v0.x + wxy[r][1] * v0.y + wxy[r][2] * v0.z + wxy[r][3] * v0.w;
                a1 += wxy[r][0] * v1.x + wxy[r][1] * v1.y + wxy[r][2] * v1.z + wxy[r][3] * v1.w;
                a2 += wxy[r][0] * v2.x + wxy[r][1] * v2.y + wxy[r][2] * v2.z + wxy[r][3] * v2.w;
            }
            ob[0] = clamp01(a0);
            ob[1] = clamp01(a1);
            ob[2] = clamp01(a2);
            cb += (size_t)3 * HW_;
            ob += (size_t)H_ * W_ * 3;
        }
    } else {
        int ix4[4];
#pragma unroll
        for (int k = 0; k < 4; ++k) ix4[k] = min(max(bx - 1 + k, 0), W_ - 1);

#pragma unroll 1
        for (int bb = 0; bb < B_ / NBS; ++bb) {
            float a0 = 0.f, a1 = 0.f, a2 = 0.f;
#pragma unroll
            for (int r = 0; r < 4; ++r)
#pragma unroll
                for (int k = 0; k < 4; ++k) {
                    float wk = wxy[r][k];
                    a0 += wk * cb[iyW[r] + ix4[k]];
                    a1 += wk * cb[HW_ + iyW[r] + ix4[k]];
                    a2 += wk * cb[2 * HW_ + iyW[r] + ix4[k]];
                }
            ob[0] = clamp01(a0);
            ob[1] = clamp01(a1);
            ob[2] = clamp01(a2);
            cb += (size_t)3 * HW_;
            ob += (size_t)H_ * W_ * 3;
        }
    }
}

extern "C" void kernel_launch(void* const* d_in, const int* in_sizes, int n_in,
                              void* d_out, int out_size, void* d_ws, size_t ws_size,
                              hipStream_t stream) {
    const float* x = (const float*)d_in[0];      // [32,256,1024,3]
    const float* disp = (const float*)d_in[1];   // [2,3,3]
    float* out = (float*)d_out;

    char* ws = (char*)d_ws;
    float* coefP = (float*)ws;                                 // 96 MiB planar
    float* dy = (float*)(ws + 100663296ull);                   // 1 MiB
    float* dx = (float*)(ws + 100663296ull + 1048576ull);      // 1 MiB

    k_disp<<<dim3((H_ * W_) / 256), dim3(256), 0, stream>>>(disp, dy, dx);

    k_wfilt<<<dim3(B_ * H_), dim3(256), 0, stream>>>(x, coefP);

    k_hfilt<<<dim3(W_ / 32, B_ * 3), dim3(256), 0, stream>>>(coefP);

    dim3 g3((H_ * W_) / 256, NBS);
    k_sample<<<g3, dim3(256), 0, stream>>>(coefP, dy, dx, out);
}

// Round 5
// 144.214 us; speedup vs baseline: 1.6477x; 1.6477x over previous
//
#include <hip/hip_runtime.h>
#include <math.h>

// Elastic transform: [32,256,1024,3] fp32, 3x3 control grid displacement.
//   k_disp   : dense dy/dx fields [256,1024] from 3x3 control points
//   k_wfilt  : spline prefilter along W (17-tap mirror FIR), x -> planar coefP
//   k_hfilt  : prefilter along H, in place on planar tiles
//   k_sample : 4x4 cubic gather, one thread per (b,h,w), planar taps,
//              LDS-staged coalesced output

#define H_ 256
#define W_ 1024
#define B_ 32
#define RAD 8                // |z|^9 trunc error ~3e-5 * gain ~ 1e-4 << 2e-2
#define ROWF 3072            // W_*3 floats per (b,h) row of x
#define HW_ (H_ * W_)        // 262144 floats per plane

typedef float f4a __attribute__((ext_vector_type(4), aligned(4)));

__device__ __forceinline__ float b3f(float t) {
    float a = fabsf(t);
    if (a < 1.0f) return (4.0f - 6.0f * a * a + 3.0f * a * a * a) * (1.0f / 6.0f);
    if (a < 2.0f) { float s = 2.0f - a; return s * s * s * (1.0f / 6.0f); }
    return 0.0f;
}

// branch-free cubic weights: w[k] = b3f(f - (k-1)), f in [0,1)
__device__ __forceinline__ void cubw(float f, float* w) {
    float f2 = f * f, f3 = f2 * f;
    float om = 1.0f - f;
    w[0] = om * om * om * (1.0f / 6.0f);
    w[1] = (3.0f * f3 - 6.0f * f2 + 4.0f) * (1.0f / 6.0f);
    w[2] = (-3.0f * f3 + 3.0f * f2 + 3.0f * f + 1.0f) * (1.0f / 6.0f);
    w[3] = f3 * (1.0f / 6.0f);
}

__device__ __forceinline__ float clamp01(float v) {
    return fminf(fmaxf(v, 0.0f), 1.0f);
}

__device__ __forceinline__ void basis3(int i, int n, float& w0, float& w1, float& w2) {
    float u = (float)i * 2.0f / (float)(n - 1);
    int base = (int)floorf(u);
    w0 = w1 = w2 = 0.0f;
#pragma unroll
    for (int k = -1; k < 3; ++k) {
        int id = base + k;
        float bw = b3f(u - (float)id);
        int j = id < 0 ? -id : id;
        j &= 3;
        if (j == 3) j = 1;
        if (j == 0) w0 += bw; else if (j == 1) w1 += bw; else w2 += bw;
    }
}

// ---------------- kernel 0: displacement fields ----------------
__global__ __launch_bounds__(256) void k_disp(const float* __restrict__ disp,
                                              float* __restrict__ dyp,
                                              float* __restrict__ dxp) {
    int idx = blockIdx.x * 256 + threadIdx.x;
    int h = idx >> 10, w = idx & 1023;

    const float A[3][3] = {{1.75f, -1.0f, 0.25f},
                           {-0.5f,  2.0f, -0.5f},
                           {0.25f, -1.0f, 1.75f}};
    float Ty[3][3], Tx[3][3];
#pragma unroll
    for (int i = 0; i < 3; ++i)
#pragma unroll
        for (int j = 0; j < 3; ++j) {
            float ty = 0.f, tx = 0.f;
#pragma unroll
            for (int k = 0; k < 3; ++k) {
                ty += A[i][k] * (5.0f * disp[k * 3 + j]);
                tx += A[i][k] * (5.0f * disp[9 + k * 3 + j]);
            }
            Ty[i][j] = ty; Tx[i][j] = tx;
        }
    float Cy[3][3], Cx[3][3];
#pragma unroll
    for (int i = 0; i < 3; ++i)
#pragma unroll
        for (int j = 0; j < 3; ++j) {
            float ty = 0.f, tx = 0.f;
#pragma unroll
            for (int k = 0; k < 3; ++k) {
                ty += Ty[i][k] * A[j][k];
                tx += Tx[i][k] * A[j][k];
            }
            Cy[i][j] = ty; Cx[i][j] = tx;
        }

    float rh0, rh1, rh2, rw0, rw1, rw2;
    basis3(h, H_, rh0, rh1, rh2);
    basis3(w, W_, rw0, rw1, rw2);
    float rh[3] = {rh0, rh1, rh2}, rw[3] = {rw0, rw1, rw2};

    float dy = 0.f, dx = 0.f;
#pragma unroll
    for (int i = 0; i < 3; ++i)
#pragma unroll
        for (int j = 0; j < 3; ++j) {
            dy += rh[i] * Cy[i][j] * rw[j];
            dx += rh[i] * Cx[i][j] * rw[j];
        }
    dyp[idx] = dy;
    dxp[idx] = dx;
}

// ---------------- kernel 1: prefilter along W, x -> planar coefP ----------
// layout per channel: [8 halo][1024][8 halo] = 1040, padded stride 1040 (%4==0)
#define PLN 1040
__global__ __launch_bounds__(256) void k_wfilt(const float* __restrict__ x,
                                               float* __restrict__ coefP) {
    __shared__ float pl[3 * PLN];        // 12480 B
    const int bp = blockIdx.x;           // b*256 + h
    const int t = threadIdx.x;
    const float* row = x + (size_t)bp * ROWF;

    {
        float4 v0 = *(const float4*)(row + 12 * t);
        float4 v1 = *(const float4*)(row + 12 * t + 4);
        float4 v2 = *(const float4*)(row + 12 * t + 8);
        // deinterleave to channel-contiguous float4s -> conflict-free b128
        float4 c0, c1, c2;
        c0.x = v0.x; c0.y = v0.w; c0.z = v1.z; c0.w = v2.y;
        c1.x = v0.y; c1.y = v1.x; c1.z = v1.w; c1.w = v2.z;
        c2.x = v0.z; c2.y = v1.y; c2.z = v2.x; c2.w = v2.w;
        *(float4*)(pl + 0 * PLN + 8 + 4 * t) = c0;
        *(float4*)(pl + 1 * PLN + 8 + 4 * t) = c1;
        *(float4*)(pl + 2 * PLN + 8 + 4 * t) = c2;
    }
    __syncthreads();

    if (t < 48) {                        // mirror halos: 3 ch x (8 left + 8 right)
        int c = t >> 4, i = t & 15;
        float* p = pl + c * PLN;
        if (i < 8) { int j = i + 1; p[8 - j] = p[8 + j]; }
        else { int r = i - 8; p[1032 + r] = p[1030 - r]; }
    }
    __syncthreads();

    float g[RAD + 1];
    g[0] = 1.7320508075688773f;
#pragma unroll
    for (int k = 1; k <= RAD; ++k) g[k] = g[k - 1] * (-0.26794919243112270647f);

    const int b = bp >> 8, h = bp & 255;
    float* dst0 = coefP + ((size_t)(b * 3) * H_ + h) * W_ + 4 * t;

#pragma unroll
    for (int c = 0; c < 3; ++c) {
        const float* p = pl + c * PLN + 4 * t;   // phys addr of col q0-8, aligned
        float w[20];
#pragma unroll
        for (int i = 0; i < 5; ++i) {
            float4 v = *(const float4*)(p + 4 * i);
            w[4 * i] = v.x; w[4 * i + 1] = v.y; w[4 * i + 2] = v.z; w[4 * i + 3] = v.w;
        }
        float4 o;
        float a0 = 0.f, a1 = 0.f, a2 = 0.f, a3 = 0.f;
#pragma unroll
        for (int k = -RAD; k <= RAD; ++k) {
            float gk = g[k < 0 ? -k : k];
            a0 += gk * w[0 + RAD + k];
            a1 += gk * w[1 + RAD + k];
            a2 += gk * w[2 + RAD + k];
            a3 += gk * w[3 + RAD + k];
        }
        o.x = a0; o.y = a1; o.z = a2; o.w = a3;
        *(float4*)(dst0 + (size_t)c * HW_) = o;   // planar, coalesced
    }
}

// ---------------- kernel 2: prefilter along H, in place on planar ---------
// block per (plane, 32-wide w-chunk); LDS tile [256][40] floats.
// lanes 0-7 share a row per b128 -> conflict-free with stride 40.
#define TSTR 40
__global__ __launch_bounds__(256) void k_hfilt(float* __restrict__ coefP) {
    __shared__ float tile[H_ * TSTR];   // 40 KiB
    const int t = threadIdx.x;
    float* src = coefP + (size_t)blockIdx.y * HW_ + blockIdx.x * 32;

#pragma unroll
    for (int it = 0; it < 8; ++it) {
        int idx = t + it * 256;          // 0..2047 float4s
        int r = idx >> 3, seg = idx & 7;
        *(float4*)(tile + r * TSTR + seg * 4) =
            *(const float4*)(src + (size_t)r * W_ + seg * 4);
    }
    __syncthreads();

    float g[RAD + 1];
    g[0] = 1.7320508075688773f;
#pragma unroll
    for (int k = 1; k <= RAD; ++k) g[k] = g[k - 1] * (-0.26794919243112270647f);

    const int cg = t & 7;          // float4 column group
    const int prow = t >> 3;       // 0..31
    const int p0 = prow * 8;

    float acc[8][4];
#pragma unroll
    for (int j = 0; j < 8; ++j) {
        acc[j][0] = 0.f; acc[j][1] = 0.f; acc[j][2] = 0.f; acc[j][3] = 0.f;
    }

#pragma unroll
    for (int r = 0; r < 8 + 2 * RAD; ++r) {    // 24 rows
        int hh = p0 - RAD + r;
        int m1 = hh < 0 ? -hh : hh;
        int m2 = 2 * (H_ - 1) - hh;            // 510 - hh
        int mp = m1 < m2 ? m1 : m2;
        float4 v = *(const float4*)(tile + mp * TSTR + cg * 4);
#pragma unroll
        for (int j = 0; j < 8; ++j) {
            const int d = r - RAD - j;         // compile-time tap
            if (d >= -RAD && d <= RAD) {
                const float wgt = g[d < 0 ? -d : d];
                acc[j][0] += wgt * v.x;
                acc[j][1] += wgt * v.y;
                acc[j][2] += wgt * v.z;
                acc[j][3] += wgt * v.w;
            }
        }
    }

#pragma unroll
    for (int j = 0; j < 8; ++j) {
        float4 o;
        o.x = acc[j][0]; o.y = acc[j][1]; o.z = acc[j][2]; o.w = acc[j][3];
        *(float4*)(src + (size_t)(p0 + j) * W_ + cg * 4) = o;
    }
}

// ---------------- kernel 3: 4x4 cubic gather, full batch parallel ---------
// grid (1024, 32): thread owns one (b, h, w). Planar taps, LDS-staged output.
__global__ __launch_bounds__(256) void k_sample(const float* __restrict__ coefP,
                                                const float* __restrict__ dyp,
                                                const float* __restrict__ dxp,
                                                float* __restrict__ out) {
    __shared__ float os[768];
    const int t = threadIdx.x;
    const int hw = blockIdx.x * 256 + t;
    const int b = blockIdx.y;
    const int h = hw >> 10, w = hw & 1023;

    float cy = (float)h + dyp[hw];
    float cx = (float)w + dxp[hw];
    float byf = floorf(cy), bxf = floorf(cx);
    int by = (int)byf, bx = (int)bxf;
    float wy[4], wx[4];
    cubw(cy - byf, wy);
    cubw(cx - bxf, wx);

    int iyW[4];
#pragma unroll
    for (int r = 0; r < 4; ++r)
        iyW[r] = min(max(by - 1 + r, 0), H_ - 1) * W_;

    const float* cb = coefP + (size_t)(b * 3) * HW_;
    float a0 = 0.f, a1 = 0.f, a2 = 0.f;

    if (bx >= 1 && bx <= W_ - 3) {
        int offr[4];
#pragma unroll
        for (int r = 0; r < 4; ++r) offr[r] = iyW[r] + bx - 1;
#pragma unroll
        for (int r = 0; r < 4; ++r) {
            f4a v0 = *(const f4a*)(cb + offr[r]);
            f4a v1 = *(const f4a*)(cb + HW_ + offr[r]);
            f4a v2 = *(const f4a*)(cb + 2 * HW_ + offr[r]);
            float wyr = wy[r];
            a0 += wyr * (wx[0] * v0.x + wx[1] * v0.y + wx[2] * v0.z + wx[3] * v0.w);
            a1 += wyr * (wx[0] * v1.x + wx[1] * v1.y + wx[2] * v1.z + wx[3] * v1.w);
            a2 += wyr * (wx[0] * v2.x + wx[1] * v2.y + wx[2] * v2.z + wx[3] * v2.w);
        }
    } else {
        int ix4[4];
#pragma unroll
        for (int k = 0; k < 4; ++k) ix4[k] = min(max(bx - 1 + k, 0), W_ - 1);
#pragma unroll
        for (int r = 0; r < 4; ++r) {
            float wyr = wy[r];
#pragma unroll
            for (int k = 0; k < 4; ++k) {
                float wk = wyr * wx[k];
                a0 += wk * cb[iyW[r] + ix4[k]];
                a1 += wk * cb[HW_ + iyW[r] + ix4[k]];
                a2 += wk * cb[2 * HW_ + iyW[r] + ix4[k]];
            }
        }
    }

    os[3 * t + 0] = clamp01(a0);
    os[3 * t + 1] = clamp01(a1);
    os[3 * t + 2] = clamp01(a2);
    __syncthreads();

    if (t < 192) {
        float4 v = *(const float4*)(os + 4 * t);
        *(float4*)(out + ((size_t)b * HW_ + (size_t)blockIdx.x * 256) * 3 + 4 * t) = v;
    }
}

extern "C" void kernel_launch(void* const* d_in, const int* in_sizes, int n_in,
                              void* d_out, int out_size, void* d_ws, size_t ws_size,
                              hipStream_t stream) {
    const float* x = (const float*)d_in[0];      // [32,256,1024,3]
    const float* disp = (const float*)d_in[1];   // [2,3,3]
    float* out = (float*)d_out;

    char* ws = (char*)d_ws;
    float* coefP = (float*)ws;                                 // 96 MiB planar
    float* dy = (float*)(ws + 100663296ull);                   // 1 MiB
    float* dx = (float*)(ws + 100663296ull + 1048576ull);      // 1 MiB

    k_disp<<<dim3((H_ * W_) / 256), dim3(256), 0, stream>>>(disp, dy, dx);

    k_wfilt<<<dim3(B_ * H_), dim3(256), 0, stream>>>(x, coefP);

    k_hfilt<<<dim3(W_ / 32, B_ * 3), dim3(256), 0, stream>>>(coefP);

    dim3 g3((H_ * W_) / 256, B_);
    k_sample<<<g3, dim3(256), 0, stream>>>(coefP, dy, dx, out);
}